// Round 3
// baseline (642.453 us; speedup 1.0000x reference)
//
#include <hip/hip_runtime.h>
#include <hip/hip_bf16.h>

// Problem constants (fixed by reference setup_inputs):
//   K3=27, PAIRS_PER_K=131072 (=2^17), N_VOX=262144 (=2^18), C_IN=C_OUT=32
//   M = 3,538,944 pairs. out = [262144][32] fp32.
//
// History: R1 113M fp32 atomics = 5.9ms. R2 per-thread LDS W = 3x FMA floor.
// R3 scalar gather latency-bound. R4 MFMA gather 312us. R5 dist-4 prefetch
// regressed (VALU 2.4x, occupancy halved). R6 runtime-indexed private arrays
// -> scratch. RULE: no runtime-indexed private arrays. R7 split-k 497us
// (gather 296, VGPR 48, occ 54%): overflow loop ~12 serial trips/wave.
// R8 560us: T2 round worked (MfmaUtil 2->8) BUT hi/lo W split ballooned
// VGPR 48->108, occ 54->22% -> gather flat 299; atomicExch claim cascade
// (dependent 2-3 trip chain per colliding wave) cost +60us vs passA/passB;
// absmax identical with/without W-lo => error is A-side bf16, W split useless.
// R9 (this): keep T2 dense round; drop W-lo (hi only, 28 MFMA/wave);
// revert claim to passA store + passB finalize (losers exch into T2, only
// displaced go to ovf); issue both rounds' probes + speculative ovf loads
// up-front so staging latency overlaps probe latency; __launch_bounds__
// (256,6) caps VGPR at 84 to protect occupancy.

#define N_VOX    262144
#define LOG2_NV  18
#define C_CH     32
#define K3       27
#define LOG2_PPK 17
#define BLOCK    256
#define FLAG_FIN 0x40000000
#define ECAP     4096
#define PLPAD    36   // plane row stride: rows differ by 36%32=4 -> 2-way max
#define FRAGN    (K3 * 2 * 64)   // uint4 fragments (hi-precision W only)

typedef __attribute__((ext_vector_type(8))) short bf16x8;
typedef __attribute__((ext_vector_type(4))) float f32x4;

__device__ __forceinline__ unsigned short f2bf(float f) {
  union { __hip_bfloat16 h; unsigned short u; } cv;
  cv.h = __float2bfloat16(f);
  return cv.u;
}

// ---------------------------------------------------------------------------
// Pass A: last-writer-wins claim (plain stores, no atomics).
__global__ __launch_bounds__(BLOCK) void passA_kernel(
    const int2* __restrict__ nbmap, int* __restrict__ T, int M) {
  int p = blockIdx.x * BLOCK + threadIdx.x;
  if (p >= M) return;
  int2 nb = nbmap[p];
  int k = p >> LOG2_PPK;
  T[(k << LOG2_NV) + nb.y] = p;
}

// Pass B: winners finalize (FLAG|in_idx); losers exch into T2 (one atomic
// each, independent chains); T2-displaced -> per-voxel overflow list;
// list overflow -> emergency list.
__global__ __launch_bounds__(BLOCK) void passB_kernel(
    const int2* __restrict__ nbmap, int* __restrict__ T, int* __restrict__ T2,
    int use2, int* __restrict__ ovf_cnt, int* __restrict__ ovf, int S2,
    int* __restrict__ ecnt, int2* __restrict__ elist, int M) {
  int p = blockIdx.x * BLOCK + threadIdx.x;
  if (p >= M) return;
  int2 nb = nbmap[p];
  int k = p >> LOG2_PPK;
  int idx = (k << LOG2_NV) + nb.y;
  if (T[idx] == p) {                          // p < 2^22 < FLAG: unambiguous
    T[idx] = FLAG_FIN | nb.x;
    return;
  }
  int val = nb.x;
  if (use2) {
    val = atomicExch(&T2[idx], val);          // loser takes second slot
    if (val < 0) return;                      // first loser: done
  }
  int pos = atomicAdd(&ovf_cnt[nb.y], 1);
  if (pos < S2) {
    ovf[(pos << LOG2_NV) + nb.y] = (k << LOG2_NV) | val;
  } else {
    int ep = atomicAdd(ecnt, 1);
    if (ep < ECAP) elist[ep] = make_int2(nb.y, (k << LOG2_NV) | val);
  }
}

// ---------------------------------------------------------------------------
// B-fragment prep: W pre-permuted into mfma_16x16x32 B-operand lane layout
// (mirror of verified A layout A[m=lane&15][k=quad*8+j], m89/m91).
__global__ __launch_bounds__(BLOCK) void bf_prep_kernel(
    const float* __restrict__ kernel_w, unsigned short* __restrict__ Bf) {
  int tid = blockIdx.x * BLOCK + threadIdx.x;
  if (tid >= FRAGN) return;
  int lane = tid & 63;
  int kc = tid >> 6;
  int k = kc >> 1, t = kc & 1;
  int i0 = (lane >> 4) * 8;
  int c = t * 16 + (lane & 15);
  union { unsigned short u[8]; uint4 v; } pk;
#pragma unroll
  for (int j = 0; j < 8; ++j)
    pk.u[j] = f2bf(kernel_w[(k << 10) + (i0 + j) * C_CH + c]);
  ((uint4*)Bf)[tid] = pk.v;
}

// ---------------------------------------------------------------------------
// Split-k MFMA gather: block = 4 waves x 16 voxels (same 16 for all waves).
// Wave w owns k in [7w, 7w+kn). All probe loads (T and T2) and speculative
// ovf loads issue up-front (one overlapped latency trip), then per round:
// 7 rows (1 trip) + 14 MFMA, R[] registers reused across rounds.
// Residual overflow (~7/block) on the fp32 serial path, dist-1 prefetch.
__global__ __launch_bounds__(BLOCK, 6) void gather_splitk_kernel(
    const float* __restrict__ in_feature,
    const float* __restrict__ kernel_w,
    const float* __restrict__ bias,
    const int* __restrict__ T,
    const int* __restrict__ T2, int use2,
    const int* __restrict__ ovf_cnt,
    const int* __restrict__ ovf,
    const unsigned short* __restrict__ Bf,
    float* __restrict__ out, int S2) {
  __shared__ float plane[4][16][PLPAD];       // 9216 B: per-wave partials
  __shared__ int flatE[256];                  // block's overflow entries
  __shared__ int scnt[16];

  const int tid = threadIdx.x;
  const int w = tid >> 6;
  const int lane = tid & 63;
  const int r16 = lane & 15;
  const int quad = lane >> 4;
  const int vb = blockIdx.x << 4;

  // ---- issue ALL independent loads up front (one overlapped trip) ----
  const int er = tid & 15;                    // (er, ej): voxel, list pos
  const int ej = tid >> 4;
  int eval = 0;
  if (ej < S2)                                // speculative; masked by scnt
    eval = ovf[(ej << LOG2_NV) + vb + er];
  if (tid < 16) {
    int c = ovf_cnt[vb + tid];
    scnt[tid] = c < S2 ? c : S2;
  }

  const int kb = w * 7;
  const int kn = (w == 3) ? 6 : 7;
  const int v = vb + r16;
  int tv[7], tv2[7];
#pragma unroll
  for (int d = 0; d < 7; ++d)
    tv[d] = (d < kn) ? T[((kb + d) << LOG2_NV) + v] : -1;
  if (use2) {
#pragma unroll
    for (int d = 0; d < 7; ++d)
      tv2[d] = (d < kn) ? T2[((kb + d) << LOG2_NV) + v] : -1;
  } else {
#pragma unroll
    for (int d = 0; d < 7; ++d) tv2[d] = -1;
  }
  __syncthreads();                            // scnt ready

  // ---- overflow staging: scalar prefix (no priv arrays), flatE write ----
  int myb = 0, tot = 0;
#pragma unroll
  for (int q = 0; q < 16; ++q) {
    int cq = scnt[q];
    if (q < er) myb += cq;
    tot += cq;
  }
  if (ej < scnt[er])
    flatE[myb + ej] = (er << 24) | eval;
  __syncthreads();                            // flatE ready

  // ---- dense rounds: T (round 0), T2 (round 1 if use2) ----
  f32x4 acc0 = {0.f, 0.f, 0.f, 0.f};
  f32x4 acc1 = {0.f, 0.f, 0.f, 0.f};
  const uint4* bfp = (const uint4*)Bf;
  const int nr = 1 + use2;
#pragma unroll 1
  for (int rnd = 0; rnd < nr; ++rnd) {
    // rows: one round trip (invalid -> row0 + zero mask)
    bf16x8 R[7];
#pragma unroll
    for (int d = 0; d < 7; ++d) {
      int t = (rnd == 0) ? tv[d] : tv2[d];
      int in = (t >= 0) ? (t & 0x3FFFF) : 0;
      const float4* ap = (const float4*)(in_feature + (in << 5) + (quad << 3));
      float4 f0 = ap[0], f1 = ap[1];
      bf16x8 a;
      a[0] = (short)f2bf(f0.x); a[1] = (short)f2bf(f0.y);
      a[2] = (short)f2bf(f0.z); a[3] = (short)f2bf(f0.w);
      a[4] = (short)f2bf(f1.x); a[5] = (short)f2bf(f1.y);
      a[6] = (short)f2bf(f1.z); a[7] = (short)f2bf(f1.w);
      if (t < 0) a = (bf16x8)0;
      R[d] = a;
    }
    // MFMAs: 2 per d (hi-precision W only — R8 proved lo-split no-op)
#pragma unroll
    for (int d = 0; d < 7; ++d) {
      if (d < kn) {
        int k = kb + d;
        uint4 h0 = bfp[(k * 2 + 0) * 64 + lane];
        uint4 h1 = bfp[(k * 2 + 1) * 64 + lane];
        acc0 = __builtin_amdgcn_mfma_f32_16x16x32_bf16(
            R[d], *reinterpret_cast<const bf16x8*>(&h0), acc0, 0, 0, 0);
        acc1 = __builtin_amdgcn_mfma_f32_16x16x32_bf16(
            R[d], *reinterpret_cast<const bf16x8*>(&h1), acc1, 0, 0, 0);
      }
    }
  }

  // ---- dump partials (C/D: col=lane&15, row=quad*4+reg — m89/m91) ----
#pragma unroll
  for (int reg = 0; reg < 4; ++reg) {
    int row = quad * 4 + reg;
    plane[w][row][r16] = acc0[reg];
    plane[w][row][16 + r16] = acc1[reg];
  }

  // ---- residual overflow: entries i = w, w+4, ... ; dist-1 prefetch ----
  const int c32 = lane & 31, h = lane >> 5;
  int i = w;
  int e_cur = 0;
  float4 p0, p1, p2, p3;
  if (i < tot) {
    e_cur = flatE[i];
    const float4* ar =
        (const float4*)(in_feature + ((e_cur & 0x3FFFF) << 5) + (h << 4));
    p0 = ar[0]; p1 = ar[1]; p2 = ar[2]; p3 = ar[3];
  }
  while (i < tot) {
    const int e = e_cur;
    float4 q0 = p0, q1 = p1, q2 = p2, q3 = p3;
    const int inext = i + 4;
    if (inext < tot) {
      e_cur = flatE[inext];
      const float4* ar =
          (const float4*)(in_feature + ((e_cur & 0x3FFFF) << 5) + (h << 4));
      p0 = ar[0]; p1 = ar[1]; p2 = ar[2]; p3 = ar[3];
    }
    const int k2 = (e >> LOG2_NV) & 31;
    const int rr = (e >> 24) & 15;
    const float* wcol = kernel_w + (k2 << 10) + (h << 4) * C_CH + c32;
    float psum = 0.f;
    psum = fmaf(q0.x, wcol[0 * C_CH], psum);
    psum = fmaf(q0.y, wcol[1 * C_CH], psum);
    psum = fmaf(q0.z, wcol[2 * C_CH], psum);
    psum = fmaf(q0.w, wcol[3 * C_CH], psum);
    psum = fmaf(q1.x, wcol[4 * C_CH], psum);
    psum = fmaf(q1.y, wcol[5 * C_CH], psum);
    psum = fmaf(q1.z, wcol[6 * C_CH], psum);
    psum = fmaf(q1.w, wcol[7 * C_CH], psum);
    psum = fmaf(q2.x, wcol[8 * C_CH], psum);
    psum = fmaf(q2.y, wcol[9 * C_CH], psum);
    psum = fmaf(q2.z, wcol[10 * C_CH], psum);
    psum = fmaf(q2.w, wcol[11 * C_CH], psum);
    psum = fmaf(q3.x, wcol[12 * C_CH], psum);
    psum = fmaf(q3.y, wcol[13 * C_CH], psum);
    psum = fmaf(q3.z, wcol[14 * C_CH], psum);
    psum = fmaf(q3.w, wcol[15 * C_CH], psum);
    psum += __shfl_xor(psum, 32);
    if (h == 0) plane[w][rr][c32] += psum;    // own plane: no cross-wave race
    i = inext;
  }

  // ---- merge 4 planes + bias, one float2 store per thread ----
  __syncthreads();
  const int mr = tid >> 4;
  const int mc = (tid & 15) << 1;
  float s0 = plane[0][mr][mc] + plane[1][mr][mc] + plane[2][mr][mc] +
             plane[3][mr][mc] + bias[mc];
  float s1 = plane[0][mr][mc + 1] + plane[1][mr][mc + 1] +
             plane[2][mr][mc + 1] + plane[3][mr][mc + 1] + bias[mc + 1];
  float2 o; o.x = s0; o.y = s1;
  *(float2*)(out + ((vb + mr) << 5) + mc) = o;
}

// ---------------------------------------------------------------------------
// Emergency finisher: the ~tens of entries that overflowed S2.
__global__ __launch_bounds__(BLOCK) void emergency_kernel(
    const float* __restrict__ in_feature, const float* __restrict__ kernel_w,
    const int* __restrict__ ecnt, const int2* __restrict__ elist,
    float* __restrict__ out) {
  int e = blockIdx.x * BLOCK + threadIdx.x;
  int n = *ecnt;
  if (n > ECAP) n = ECAP;
  if (e >= n) return;
  int2 ent = elist[e];
  int v = ent.x, k = ent.y >> LOG2_NV, in = ent.y & 0x3FFFF;
  float a[C_CH];
  const float4* ar = (const float4*)(in_feature + (in << 5));
#pragma unroll
  for (int q = 0; q < 8; ++q) ((float4*)a)[q] = ar[q];
  for (int c = 0; c < C_CH; ++c) {
    float s = 0.f;
#pragma unroll
    for (int i = 0; i < C_CH; ++i)
      s = fmaf(a[i], kernel_w[(k << 10) + i * C_CH + c], s);
    atomicAdd(&out[v * C_CH + c], s);
  }
}

// ---------------------------------------------------------------------------
// Fallback (tiny ws): round-1 direct-atomic version. Correct, slow.
__global__ __launch_bounds__(BLOCK) void init_bias_kernel(
    float* __restrict__ out, const float* __restrict__ bias, int n4) {
  int idx = blockIdx.x * blockDim.x + threadIdx.x;
  if (idx >= n4) return;
  ((float4*)out)[idx] = ((const float4*)bias)[idx & 7];
}

__global__ __launch_bounds__(BLOCK) void scatter_conv_kernel(
    const float* __restrict__ in_feature, const float* __restrict__ kernel_w,
    const int* __restrict__ nbmap, float* __restrict__ out) {
  const int k = blockIdx.x >> 9;
  const int pair = blockIdx.x * BLOCK + threadIdx.x;
  const float* __restrict__ Wk = kernel_w + k * (C_CH * C_CH);
  const int2 nb = ((const int2*)nbmap)[pair];
  const float4* __restrict__ inrow =
      (const float4*)(in_feature + (long)nb.x * C_CH);
  float a[C_CH];
#pragma unroll
  for (int j = 0; j < 8; ++j) ((float4*)a)[j] = inrow[j];
  float acc[C_CH];
#pragma unroll
  for (int c = 0; c < C_CH; ++c) acc[c] = 0.0f;
#pragma unroll
  for (int i = 0; i < C_CH; ++i) {
    const float av = a[i];
#pragma unroll
    for (int c = 0; c < C_CH; ++c)
      acc[c] = fmaf(av, Wk[i * C_CH + c], acc[c]);
  }
  float* __restrict__ orow = out + (long)nb.y * C_CH;
#pragma unroll
  for (int c = 0; c < C_CH; ++c) atomicAdd(orow + c, acc[c]);
}

// ===========================================================================
extern "C" void kernel_launch(void* const* d_in, const int* in_sizes, int n_in,
                              void* d_out, int out_size, void* d_ws,
                              size_t ws_size, hipStream_t stream) {
  const float* in_feature = (const float*)d_in[0];
  const float* kernel_w   = (const float*)d_in[1];
  const float* bias       = (const float*)d_in[2];
  const int*   nbmap      = (const int*)d_in[3];
  float* out = (float*)d_out;
  const int M = in_sizes[3] / 2;                 // 3,538,944

  // ws (ints): T[27N] | T2[27N if use2] | ovf_cnt[N] | ecnt[64]
  //            | elist[2*ECAP] | Bf[13824] | ovf[S2*N]
  const long FIXED = 64 + 2 * ECAP + 13824;
  long ws_ints = (long)(ws_size / 4);
  long planes = (ws_ints - FIXED) / N_VOX;       // 1 MB planes
  int use2 = 0;
  long s2c;
  if (planes >= 58) {                            // tier 1: T + T2 + S2>=3
    use2 = 1;
    s2c = planes - 55;
    if (s2c > 7) s2c = 7;                        // residual mean 0.44/voxel
  } else {                                       // tier 2: R7-style single T
    s2c = planes - 28;
    if (s2c > 15) s2c = 15;
  }
  int S2 = (int)s2c;

  if (!use2 && S2 < 4) {                         // tier 3: direct atomics
    const int n4 = out_size / 4;
    init_bias_kernel<<<(n4 + BLOCK - 1) / BLOCK, BLOCK, 0, stream>>>(out, bias,
                                                                     n4);
    scatter_conv_kernel<<<M / BLOCK, BLOCK, 0, stream>>>(in_feature, kernel_w,
                                                         nbmap, out);
    return;
  }

  const long TPLANES = (long)K3 * N_VOX;
  int* T        = (int*)d_ws;                       // [27][N_VOX]
  int* T2       = use2 ? (T + TPLANES) : T;         // [27][N_VOX] (tier 1)
  int* ovf_cnt  = T + TPLANES * (1 + use2);         // [N_VOX]
  int* ecnt     = ovf_cnt + N_VOX;                  // [64] (use [0])
  int2* elist   = (int2*)(ecnt + 64);               // [ECAP]
  unsigned short* Bf = (unsigned short*)(ecnt + 64 + 2 * ECAP);  // [27648]
  int* ovf      = ((int*)Bf) + 13824;               // [S2][N_VOX]

  hipMemsetAsync(T, 0xFF, (size_t)TPLANES * 4 * (1 + use2), stream);
  hipMemsetAsync(ovf_cnt, 0, (size_t)(N_VOX + 64) * 4, stream);

  bf_prep_kernel<<<(FRAGN + BLOCK - 1) / BLOCK, BLOCK, 0, stream>>>(kernel_w,
                                                                    Bf);
  passA_kernel<<<M / BLOCK, BLOCK, 0, stream>>>((const int2*)nbmap, T, M);
  passB_kernel<<<M / BLOCK, BLOCK, 0, stream>>>((const int2*)nbmap, T, T2,
                                                use2, ovf_cnt, ovf, S2, ecnt,
                                                elist, M);
  gather_splitk_kernel<<<N_VOX / 16, BLOCK, 0, stream>>>(
      in_feature, kernel_w, bias, T, T2, use2, ovf_cnt, ovf, Bf, out, S2);
  emergency_kernel<<<ECAP / BLOCK, BLOCK, 0, stream>>>(in_feature, kernel_w,
                                                       ecnt, elist, out);
}

// Round 4
// 397.480 us; speedup vs baseline: 1.6163x; 1.6163x over previous
//
#include <hip/hip_runtime.h>
#include <hip/hip_bf16.h>

// Problem constants (fixed by reference setup_inputs):
//   K3=27, PAIRS_PER_K=131072 (=2^17), N_VOX=262144 (=2^18), C_IN=C_OUT=32
//   M = 3,538,944 pairs. out = [262144][32] fp32.
//
// History: R1 113M fp32 atomics = 5.9ms. R2 per-thread LDS W = 3x FMA floor.
// R3 scalar gather latency-bound. R4 MFMA gather 312us. R5 dist-4 prefetch
// regressed (VALU 2.4x, occupancy halved). R6 runtime-indexed private arrays
// -> scratch. RULE: no runtime-indexed private arrays. R7 split-k 497us
// (gather 296, VGPR 48, occ 54%): overflow loop ~12 serial trips/wave.
// R8 560us: T2 round works (MfmaUtil 2->8, ovf 46->7/block) but hi+lo W
// hoisted 28 Bf uint4 -> VGPR 108, occ 22% -> flat; one-pass exch claim
// +34us vs passA/passB (every lane waits atomic return); W-lo numerically
// no-op (absmax bit-identical). R9 642us: __launch_bounds__(256,6) forced
// VGPR 40 -> WRITE_SIZE 732MB scratch spill, gather 415. RULES: never force
// min-waves beyond live set; WRITE_SIZE explosion = spill signature;
// one-pass atomic-return claims lose to 2-pass.
// R10 (this): T2 round at restored occupancy — hi-only W (14 Bf loads,
// R7-proven 48-VGPR body), rounds loop, launch_bounds(256,4) (cap 128,
// spill-impossible since R8 needed only 108). feat16: in_feature
// pre-converted to bf16 in ws when it fits -> dense row loads 16B/lane,
// zero f2bf VALU in dense path (VALUBusy was ~1/3 of gather).

#define N_VOX    262144
#define LOG2_NV  18
#define C_CH     32
#define K3       27
#define LOG2_PPK 17
#define BLOCK    256
#define FLAG_FIN 0x40000000
#define ECAP     4096
#define PLPAD    36   // plane row stride: rows differ by 36%32=4 -> 2-way max
#define FRAGN    (K3 * 2 * 64)   // uint4 fragments (hi-precision W only)

typedef __attribute__((ext_vector_type(8))) short bf16x8;
typedef __attribute__((ext_vector_type(4))) float f32x4;

__device__ __forceinline__ unsigned short f2bf(float f) {
  union { __hip_bfloat16 h; unsigned short u; } cv;
  cv.h = __float2bfloat16(f);
  return cv.u;
}

// ---------------------------------------------------------------------------
// Pass A: last-writer-wins claim (plain stores, fire-and-forget, no atomics).
__global__ __launch_bounds__(BLOCK) void passA_kernel(
    const int2* __restrict__ nbmap, int* __restrict__ T, int M) {
  int p = blockIdx.x * BLOCK + threadIdx.x;
  if (p >= M) return;
  int2 nb = nbmap[p];
  int k = p >> LOG2_PPK;
  T[(k << LOG2_NV) + nb.y] = p;
}

// Pass B: winners finalize (FLAG|in_idx, plain store); losers exch into T2
// (one atomic, independent chains); T2-displaced -> per-voxel overflow list;
// list overflow -> emergency list.
__global__ __launch_bounds__(BLOCK) void passB_kernel(
    const int2* __restrict__ nbmap, int* __restrict__ T, int* __restrict__ T2,
    int use2, int* __restrict__ ovf_cnt, int* __restrict__ ovf, int S2,
    int* __restrict__ ecnt, int2* __restrict__ elist, int M) {
  int p = blockIdx.x * BLOCK + threadIdx.x;
  if (p >= M) return;
  int2 nb = nbmap[p];
  int k = p >> LOG2_PPK;
  int idx = (k << LOG2_NV) + nb.y;
  if (T[idx] == p) {                          // p < 2^22 < FLAG: unambiguous
    T[idx] = FLAG_FIN | nb.x;
    return;
  }
  int val = nb.x;
  if (use2) {
    val = atomicExch(&T2[idx], val);          // loser takes second slot
    if (val < 0) return;                      // first loser: done
  }
  int pos = atomicAdd(&ovf_cnt[nb.y], 1);
  if (pos < S2) {
    ovf[(pos << LOG2_NV) + nb.y] = (k << LOG2_NV) | val;
  } else {
    int ep = atomicAdd(ecnt, 1);
    if (ep < ECAP) elist[ep] = make_int2(nb.y, (k << LOG2_NV) | val);
  }
}

// ---------------------------------------------------------------------------
// B-fragment prep: W pre-permuted into mfma_16x16x32 B-operand lane layout
// (mirror of verified A layout A[m=lane&15][k=quad*8+j], m89/m91).
__global__ __launch_bounds__(BLOCK) void bf_prep_kernel(
    const float* __restrict__ kernel_w, unsigned short* __restrict__ Bf) {
  int tid = blockIdx.x * BLOCK + threadIdx.x;
  if (tid >= FRAGN) return;
  int lane = tid & 63;
  int kc = tid >> 6;
  int k = kc >> 1, t = kc & 1;
  int i0 = (lane >> 4) * 8;
  int c = t * 16 + (lane & 15);
  union { unsigned short u[8]; uint4 v; } pk;
#pragma unroll
  for (int j = 0; j < 8; ++j)
    pk.u[j] = f2bf(kernel_w[(k << 10) + (i0 + j) * C_CH + c]);
  ((uint4*)Bf)[tid] = pk.v;
}

// feat16 prep: in_feature [N_VOX][32] f32 -> bf16, row-major. One uint4
// (8 channels) per thread, fully coalesced.
__global__ __launch_bounds__(BLOCK) void feat16_prep_kernel(
    const float* __restrict__ in_feature, unsigned short* __restrict__ feat16) {
  int idx = blockIdx.x * BLOCK + threadIdx.x;   // [0, N_VOX*4)
  const float4* src = (const float4*)in_feature + (idx << 1);
  float4 f0 = src[0], f1 = src[1];
  union { unsigned short u[8]; uint4 v; } pk;
  pk.u[0] = f2bf(f0.x); pk.u[1] = f2bf(f0.y);
  pk.u[2] = f2bf(f0.z); pk.u[3] = f2bf(f0.w);
  pk.u[4] = f2bf(f1.x); pk.u[5] = f2bf(f1.y);
  pk.u[6] = f2bf(f1.z); pk.u[7] = f2bf(f1.w);
  ((uint4*)feat16)[idx] = pk.v;
}

// ---------------------------------------------------------------------------
// Split-k MFMA gather: block = 4 waves x 16 voxels (same 16 for all waves).
// Wave w owns k in [7w, 7w+kn). Per round (T, then T2 if use2): 7 probes
// (1 trip) + 7 rows (1 trip) + 14 MFMA (hi W only). Rounds loop reuses
// tv[]/R[] registers. F16: rows load 16B/lane from pre-converted feat16
// (no f2bf VALU). Residual overflow (~7/block) on the fp32 serial path.
template <int F16>
__global__ __launch_bounds__(BLOCK, 4) void gather_splitk_kernel(
    const float* __restrict__ in_feature,
    const unsigned short* __restrict__ feat16,
    const float* __restrict__ kernel_w,
    const float* __restrict__ bias,
    const int* __restrict__ T,
    const int* __restrict__ T2, int use2,
    const int* __restrict__ ovf_cnt,
    const int* __restrict__ ovf,
    const unsigned short* __restrict__ Bf,
    float* __restrict__ out, int S2) {
  __shared__ float plane[4][16][PLPAD];       // 9216 B: per-wave partials
  __shared__ int flatE[256];                  // block's overflow entries
  __shared__ int scnt[16];

  const int tid = threadIdx.x;
  const int w = tid >> 6;
  const int lane = tid & 63;
  const int r16 = lane & 15;
  const int quad = lane >> 4;
  const int vb = blockIdx.x << 4;

  // ---- overflow staging: counts, per-thread scalar prefix, entries ----
  if (tid < 16) {
    int c = ovf_cnt[vb + tid];
    scnt[tid] = c < S2 ? c : S2;
  }
  __syncthreads();
  const int er = tid & 15;                    // (er, ej): voxel, list pos
  const int ej = tid >> 4;
  int myb = 0, tot = 0;
#pragma unroll
  for (int q = 0; q < 16; ++q) {              // scalar prefix: no priv arrays
    int cq = scnt[q];
    if (q < er) myb += cq;
    tot += cq;
  }
  if (ej < scnt[er])
    flatE[myb + ej] = (er << 24) | ovf[(ej << LOG2_NV) + vb + er];
  __syncthreads();

  // ---- dense rounds: T (round 0), T2 (round 1 if use2) ----
  const int kb = w * 7;
  const int kn = (w == 3) ? 6 : 7;
  const int v = vb + r16;
  f32x4 acc0 = {0.f, 0.f, 0.f, 0.f};
  f32x4 acc1 = {0.f, 0.f, 0.f, 0.f};
  const uint4* bfp = (const uint4*)Bf;
  const int nr = 1 + use2;
#pragma unroll 1
  for (int rnd = 0; rnd < nr; ++rnd) {
    const int* Tc = (rnd == 0) ? T : T2;
    // probes: one round trip (coalesced 64B per k)
    int tv[7];
#pragma unroll
    for (int d = 0; d < 7; ++d)
      tv[d] = (d < kn) ? Tc[((kb + d) << LOG2_NV) + v] : -1;

    // rows: one round trip (invalid -> row0 + zero mask)
    bf16x8 R[7];
#pragma unroll
    for (int d = 0; d < 7; ++d) {
      int t = tv[d];
      int in = (t >= 0) ? (t & 0x3FFFF) : 0;
      bf16x8 a;
      if (F16) {
        a = *reinterpret_cast<const bf16x8*>(feat16 + (in << 5) + (quad << 3));
      } else {
        const float4* ap =
            (const float4*)(in_feature + (in << 5) + (quad << 3));
        float4 f0 = ap[0], f1 = ap[1];
        a[0] = (short)f2bf(f0.x); a[1] = (short)f2bf(f0.y);
        a[2] = (short)f2bf(f0.z); a[3] = (short)f2bf(f0.w);
        a[4] = (short)f2bf(f1.x); a[5] = (short)f2bf(f1.y);
        a[6] = (short)f2bf(f1.z); a[7] = (short)f2bf(f1.w);
      }
      if (t < 0) a = (bf16x8)0;
      R[d] = a;
    }

    // MFMAs: 2 per d (hi-precision W only — R8 proved lo-split no-op)
#pragma unroll
    for (int d = 0; d < 7; ++d) {
      if (d < kn) {
        int k = kb + d;
        uint4 h0 = bfp[(k * 2 + 0) * 64 + lane];
        uint4 h1 = bfp[(k * 2 + 1) * 64 + lane];
        acc0 = __builtin_amdgcn_mfma_f32_16x16x32_bf16(
            R[d], *reinterpret_cast<const bf16x8*>(&h0), acc0, 0, 0, 0);
        acc1 = __builtin_amdgcn_mfma_f32_16x16x32_bf16(
            R[d], *reinterpret_cast<const bf16x8*>(&h1), acc1, 0, 0, 0);
      }
    }
  }

  // ---- dump partials (C/D: col=lane&15, row=quad*4+reg — m89/m91) ----
#pragma unroll
  for (int reg = 0; reg < 4; ++reg) {
    int row = quad * 4 + reg;
    plane[w][row][r16] = acc0[reg];
    plane[w][row][16 + r16] = acc1[reg];
  }

  // ---- residual overflow: entries i = w, w+4, ... ; dist-1 prefetch ----
  const int c32 = lane & 31, h = lane >> 5;
  int i = w;
  int e_cur = 0;
  float4 p0, p1, p2, p3;
  if (i < tot) {
    e_cur = flatE[i];
    const float4* ar =
        (const float4*)(in_feature + ((e_cur & 0x3FFFF) << 5) + (h << 4));
    p0 = ar[0]; p1 = ar[1]; p2 = ar[2]; p3 = ar[3];
  }
  while (i < tot) {
    const int e = e_cur;
    float4 q0 = p0, q1 = p1, q2 = p2, q3 = p3;
    const int inext = i + 4;
    if (inext < tot) {
      e_cur = flatE[inext];
      const float4* ar =
          (const float4*)(in_feature + ((e_cur & 0x3FFFF) << 5) + (h << 4));
      p0 = ar[0]; p1 = ar[1]; p2 = ar[2]; p3 = ar[3];
    }
    const int k2 = (e >> LOG2_NV) & 31;
    const int rr = (e >> 24) & 15;
    const float* wcol = kernel_w + (k2 << 10) + (h << 4) * C_CH + c32;
    float psum = 0.f;
    psum = fmaf(q0.x, wcol[0 * C_CH], psum);
    psum = fmaf(q0.y, wcol[1 * C_CH], psum);
    psum = fmaf(q0.z, wcol[2 * C_CH], psum);
    psum = fmaf(q0.w, wcol[3 * C_CH], psum);
    psum = fmaf(q1.x, wcol[4 * C_CH], psum);
    psum = fmaf(q1.y, wcol[5 * C_CH], psum);
    psum = fmaf(q1.z, wcol[6 * C_CH], psum);
    psum = fmaf(q1.w, wcol[7 * C_CH], psum);
    psum = fmaf(q2.x, wcol[8 * C_CH], psum);
    psum = fmaf(q2.y, wcol[9 * C_CH], psum);
    psum = fmaf(q2.z, wcol[10 * C_CH], psum);
    psum = fmaf(q2.w, wcol[11 * C_CH], psum);
    psum = fmaf(q3.x, wcol[12 * C_CH], psum);
    psum = fmaf(q3.y, wcol[13 * C_CH], psum);
    psum = fmaf(q3.z, wcol[14 * C_CH], psum);
    psum = fmaf(q3.w, wcol[15 * C_CH], psum);
    psum += __shfl_xor(psum, 32);
    if (h == 0) plane[w][rr][c32] += psum;    // own plane: no cross-wave race
    i = inext;
  }

  // ---- merge 4 planes + bias, one float2 store per thread ----
  __syncthreads();
  const int mr = tid >> 4;
  const int mc = (tid & 15) << 1;
  float s0 = plane[0][mr][mc] + plane[1][mr][mc] + plane[2][mr][mc] +
             plane[3][mr][mc] + bias[mc];
  float s1 = plane[0][mr][mc + 1] + plane[1][mr][mc + 1] +
             plane[2][mr][mc + 1] + plane[3][mr][mc + 1] + bias[mc + 1];
  float2 o; o.x = s0; o.y = s1;
  *(float2*)(out + ((vb + mr) << 5) + mc) = o;
}

// ---------------------------------------------------------------------------
// Emergency finisher: the ~tens of entries that overflowed S2.
__global__ __launch_bounds__(BLOCK) void emergency_kernel(
    const float* __restrict__ in_feature, const float* __restrict__ kernel_w,
    const int* __restrict__ ecnt, const int2* __restrict__ elist,
    float* __restrict__ out) {
  int e = blockIdx.x * BLOCK + threadIdx.x;
  int n = *ecnt;
  if (n > ECAP) n = ECAP;
  if (e >= n) return;
  int2 ent = elist[e];
  int v = ent.x, k = ent.y >> LOG2_NV, in = ent.y & 0x3FFFF;
  float a[C_CH];
  const float4* ar = (const float4*)(in_feature + (in << 5));
#pragma unroll
  for (int q = 0; q < 8; ++q) ((float4*)a)[q] = ar[q];
  for (int c = 0; c < C_CH; ++c) {
    float s = 0.f;
#pragma unroll
    for (int i = 0; i < C_CH; ++i)
      s = fmaf(a[i], kernel_w[(k << 10) + i * C_CH + c], s);
    atomicAdd(&out[v * C_CH + c], s);
  }
}

// ---------------------------------------------------------------------------
// Fallback (tiny ws): round-1 direct-atomic version. Correct, slow.
__global__ __launch_bounds__(BLOCK) void init_bias_kernel(
    float* __restrict__ out, const float* __restrict__ bias, int n4) {
  int idx = blockIdx.x * blockDim.x + threadIdx.x;
  if (idx >= n4) return;
  ((float4*)out)[idx] = ((const float4*)bias)[idx & 7];
}

__global__ __launch_bounds__(BLOCK) void scatter_conv_kernel(
    const float* __restrict__ in_feature, const float* __restrict__ kernel_w,
    const int* __restrict__ nbmap, float* __restrict__ out) {
  const int k = blockIdx.x >> 9;
  const int pair = blockIdx.x * BLOCK + threadIdx.x;
  const float* __restrict__ Wk = kernel_w + k * (C_CH * C_CH);
  const int2 nb = ((const int2*)nbmap)[pair];
  const float4* __restrict__ inrow =
      (const float4*)(in_feature + (long)nb.x * C_CH);
  float a[C_CH];
#pragma unroll
  for (int j = 0; j < 8; ++j) ((float4*)a)[j] = inrow[j];
  float acc[C_CH];
#pragma unroll
  for (int c = 0; c < C_CH; ++c) acc[c] = 0.0f;
#pragma unroll
  for (int i = 0; i < C_CH; ++i) {
    const float av = a[i];
#pragma unroll
    for (int c = 0; c < C_CH; ++c)
      acc[c] = fmaf(av, Wk[i * C_CH + c], acc[c]);
  }
  float* __restrict__ orow = out + (long)nb.y * C_CH;
#pragma unroll
  for (int c = 0; c < C_CH; ++c) atomicAdd(orow + c, acc[c]);
}

// ===========================================================================
extern "C" void kernel_launch(void* const* d_in, const int* in_sizes, int n_in,
                              void* d_out, int out_size, void* d_ws,
                              size_t ws_size, hipStream_t stream) {
  const float* in_feature = (const float*)d_in[0];
  const float* kernel_w   = (const float*)d_in[1];
  const float* bias       = (const float*)d_in[2];
  const int*   nbmap      = (const int*)d_in[3];
  float* out = (float*)d_out;
  const int M = in_sizes[3] / 2;                 // 3,538,944

  // ws (ints): T[27N] | T2[27N if use2] | ovf_cnt[N] | ecnt[64]
  //            | elist[2*ECAP] | Bf[13824] | ovf[S2*N] | feat16[16N if use16]
  const long FIXED = 64 + 2 * ECAP + 13824;
  long ws_ints = (long)(ws_size / 4);
  long planes = (ws_ints - FIXED) / N_VOX;       // 1 MB planes
  int use2 = 0, use16 = 0;
  long s2c;
  if (planes >= 75) {                            // tier 0: T+T2+feat16+S2>=4
    use2 = 1; use16 = 1;
    s2c = planes - 71;
    if (s2c > 7) s2c = 7;
  } else if (planes >= 59) {                     // tier 1: T+T2+S2>=4
    use2 = 1;
    s2c = planes - 55;
    if (s2c > 7) s2c = 7;
  } else {                                       // tier 2: single T
    s2c = planes - 28;
    if (s2c > 15) s2c = 15;
  }
  int S2 = (int)s2c;

  if (!use2 && S2 < 4) {                         // tier 3: direct atomics
    const int n4 = out_size / 4;
    init_bias_kernel<<<(n4 + BLOCK - 1) / BLOCK, BLOCK, 0, stream>>>(out, bias,
                                                                     n4);
    scatter_conv_kernel<<<M / BLOCK, BLOCK, 0, stream>>>(in_feature, kernel_w,
                                                         nbmap, out);
    return;
  }

  const long TPLANES = (long)K3 * N_VOX;
  int* T        = (int*)d_ws;                       // [27][N_VOX]
  int* T2       = use2 ? (T + TPLANES) : T;         // [27][N_VOX]
  int* ovf_cnt  = T + TPLANES * (1 + use2);         // [N_VOX]
  int* ecnt     = ovf_cnt + N_VOX;                  // [64] (use [0])
  int2* elist   = (int2*)(ecnt + 64);               // [ECAP]
  unsigned short* Bf = (unsigned short*)(ecnt + 64 + 2 * ECAP);  // [27648]
  int* ovf      = ((int*)Bf) + 13824;               // [S2][N_VOX]
  unsigned short* feat16 = (unsigned short*)(ovf + (long)S2 * N_VOX);

  hipMemsetAsync(T, 0xFF, (size_t)TPLANES * 4 * (1 + use2), stream);
  hipMemsetAsync(ovf_cnt, 0, (size_t)(N_VOX + 64) * 4, stream);

  bf_prep_kernel<<<(FRAGN + BLOCK - 1) / BLOCK, BLOCK, 0, stream>>>(kernel_w,
                                                                    Bf);
  if (use16)
    feat16_prep_kernel<<<(N_VOX * 4) / BLOCK, BLOCK, 0, stream>>>(in_feature,
                                                                  feat16);
  passA_kernel<<<M / BLOCK, BLOCK, 0, stream>>>((const int2*)nbmap, T, M);
  passB_kernel<<<M / BLOCK, BLOCK, 0, stream>>>((const int2*)nbmap, T, T2,
                                                use2, ovf_cnt, ovf, S2, ecnt,
                                                elist, M);
  if (use16)
    gather_splitk_kernel<1><<<N_VOX / 16, BLOCK, 0, stream>>>(
        in_feature, feat16, kernel_w, bias, T, T2, use2, ovf_cnt, ovf, Bf,
        out, S2);
  else
    gather_splitk_kernel<0><<<N_VOX / 16, BLOCK, 0, stream>>>(
        in_feature, feat16, kernel_w, bias, T, T2, use2, ovf_cnt, ovf, Bf,
        out, S2);
  emergency_kernel<<<ECAP / BLOCK, BLOCK, 0, stream>>>(in_feature, kernel_w,
                                                       ecnt, elist, out);
}

// Round 5
// 389.065 us; speedup vs baseline: 1.6513x; 1.0216x over previous
//
#include <hip/hip_runtime.h>
#include <hip/hip_bf16.h>

// Problem constants (fixed by reference setup_inputs):
//   K3=27, PAIRS_PER_K=131072 (=2^17), N_VOX=262144 (=2^18), C_IN=C_OUT=32
//   M = 3,538,944 pairs. out = [262144][32] fp32.
//
// History: R1 113M fp32 atomics = 5.9ms. R2 per-thread LDS W = 3x FMA floor.
// R3 scalar gather latency-bound. R4 MFMA gather 312us. R5 dist-4 prefetch
// regressed. R6 runtime-indexed private arrays -> scratch. RULE: no
// runtime-indexed private arrays. R7 split-k 497us (gather 296, 48 VGPR).
// R8 560us: T2 round works (ovf 46->7/block) but hi+lo W -> VGPR 108,
// occ 22% -> flat; one-pass atomic-return claim loses to 2-pass; W-lo
// numerically no-op. R9 642us: forced min-waves -> VGPR 40, WRITE_SIZE
// 732MB scratch spill, gather 415. RULES: never force min-waves beyond
// live set; WRITE_SIZE explosion = spill signature. R10 397us: T2 round
// at 64 VGPR / occ 43% + feat16 bf16 table -> gather 154us. WRITE 96MB =
// out 32MB + passB dirty-line evictions (not spill).
// R11 (this): (a) gather issues BOTH rounds' probes then BOTH rounds'
// rows before any MFMA -> dependent chain 4 hops -> 2 (R0+R1 live = 56
// VGPR, total ~110 < 128 cap, spill-impossible); (b) claim passes handle
// 2 pairs/thread (int4 nbmap) -> half the waves, 2x MLP per thread in the
// random-touch phase.

#define N_VOX    262144
#define LOG2_NV  18
#define C_CH     32
#define K3       27
#define LOG2_PPK 17
#define BLOCK    256
#define FLAG_FIN 0x40000000
#define ECAP     4096
#define PLPAD    36   // plane row stride: rows differ by 36%32=4 -> 2-way max
#define FRAGN    (K3 * 2 * 64)   // uint4 fragments (hi-precision W only)

typedef __attribute__((ext_vector_type(8))) short bf16x8;
typedef __attribute__((ext_vector_type(4))) float f32x4;

__device__ __forceinline__ unsigned short f2bf(float f) {
  union { __hip_bfloat16 h; unsigned short u; } cv;
  cv.h = __float2bfloat16(f);
  return cv.u;
}

// ---------------------------------------------------------------------------
// Pass A: last-writer-wins claim (plain stores, fire-and-forget).
// 2 pairs/thread: int4 load, two independent random stores.
__global__ __launch_bounds__(BLOCK) void passA_kernel(
    const int4* __restrict__ nbmap2, int* __restrict__ T, int Mh) {
  int q = blockIdx.x * BLOCK + threadIdx.x;
  if (q >= Mh) return;
  int4 nb = nbmap2[q];
  int p0 = q << 1, p1 = (q << 1) | 1;
  T[((p0 >> LOG2_PPK) << LOG2_NV) + nb.y] = p0;
  T[((p1 >> LOG2_PPK) << LOG2_NV) + nb.w] = p1;
}

// Loser path: exch into T2 (one atomic, independent chains); displaced ->
// per-voxel overflow list; list overflow -> emergency list.
__device__ __forceinline__ void loser_path(
    int vox, int k, int in, int* __restrict__ T2, int idx, int use2,
    int* __restrict__ ovf_cnt, int* __restrict__ ovf, int S2,
    int* __restrict__ ecnt, int2* __restrict__ elist) {
  int val = in;
  if (use2) {
    val = atomicExch(&T2[idx], val);          // loser takes second slot
    if (val < 0) return;                      // first loser: done
  }
  int pos = atomicAdd(&ovf_cnt[vox], 1);
  if (pos < S2) {
    ovf[(pos << LOG2_NV) + vox] = (k << LOG2_NV) | val;
  } else {
    int ep = atomicAdd(ecnt, 1);
    if (ep < ECAP) elist[ep] = make_int2(vox, (k << LOG2_NV) | val);
  }
}

// Pass B: winners finalize (FLAG|in_idx, plain store); losers -> loser_path.
// 2 pairs/thread; both T reads issued before either resolution (MLP).
__global__ __launch_bounds__(BLOCK) void passB_kernel(
    const int4* __restrict__ nbmap2, int* __restrict__ T, int* __restrict__ T2,
    int use2, int* __restrict__ ovf_cnt, int* __restrict__ ovf, int S2,
    int* __restrict__ ecnt, int2* __restrict__ elist, int Mh) {
  int q = blockIdx.x * BLOCK + threadIdx.x;
  if (q >= Mh) return;
  int4 nb = nbmap2[q];
  int p0 = q << 1, p1 = (q << 1) | 1;
  int k0 = p0 >> LOG2_PPK, k1 = p1 >> LOG2_PPK;
  int idx0 = (k0 << LOG2_NV) + nb.y;
  int idx1 = (k1 << LOG2_NV) + nb.w;
  int t0 = T[idx0];                           // both loads in flight
  int t1 = T[idx1];
  if (t0 == p0) {                             // p < 2^22 < FLAG: unambiguous
    T[idx0] = FLAG_FIN | nb.x;
  } else {
    loser_path(nb.y, k0, nb.x, T2, idx0, use2, ovf_cnt, ovf, S2, ecnt, elist);
  }
  if (t1 == p1) {
    T[idx1] = FLAG_FIN | nb.z;
  } else {
    loser_path(nb.w, k1, nb.z, T2, idx1, use2, ovf_cnt, ovf, S2, ecnt, elist);
  }
}

// ---------------------------------------------------------------------------
// B-fragment prep: W pre-permuted into mfma_16x16x32 B-operand lane layout
// (mirror of verified A layout A[m=lane&15][k=quad*8+j], m89/m91).
__global__ __launch_bounds__(BLOCK) void bf_prep_kernel(
    const float* __restrict__ kernel_w, unsigned short* __restrict__ Bf) {
  int tid = blockIdx.x * BLOCK + threadIdx.x;
  if (tid >= FRAGN) return;
  int lane = tid & 63;
  int kc = tid >> 6;
  int k = kc >> 1, t = kc & 1;
  int i0 = (lane >> 4) * 8;
  int c = t * 16 + (lane & 15);
  union { unsigned short u[8]; uint4 v; } pk;
#pragma unroll
  for (int j = 0; j < 8; ++j)
    pk.u[j] = f2bf(kernel_w[(k << 10) + (i0 + j) * C_CH + c]);
  ((uint4*)Bf)[tid] = pk.v;
}

// feat16 prep: in_feature [N_VOX][32] f32 -> bf16, row-major. One uint4
// (8 channels) per thread, fully coalesced.
__global__ __launch_bounds__(BLOCK) void feat16_prep_kernel(
    const float* __restrict__ in_feature, unsigned short* __restrict__ feat16) {
  int idx = blockIdx.x * BLOCK + threadIdx.x;   // [0, N_VOX*4)
  const float4* src = (const float4*)in_feature + (idx << 1);
  float4 f0 = src[0], f1 = src[1];
  union { unsigned short u[8]; uint4 v; } pk;
  pk.u[0] = f2bf(f0.x); pk.u[1] = f2bf(f0.y);
  pk.u[2] = f2bf(f0.z); pk.u[3] = f2bf(f0.w);
  pk.u[4] = f2bf(f1.x); pk.u[5] = f2bf(f1.y);
  pk.u[6] = f2bf(f1.z); pk.u[7] = f2bf(f1.w);
  ((uint4*)feat16)[idx] = pk.v;
}

// ---------------------------------------------------------------------------
// Split-k MFMA gather: block = 4 waves x 16 voxels (same 16 for all waves).
// Wave w owns k in [7w, 7w+kn). ALL probes (T and T2) issue first, then ALL
// rows (R0 and R1), then both MFMA sweeps: dependent chain = probes->rows,
// 2 hops instead of 4. F16: rows load 16B/lane from pre-converted feat16.
// Residual overflow (~7/block) on the fp32 serial path, dist-1 prefetch.
template <int F16>
__global__ __launch_bounds__(BLOCK, 4) void gather_splitk_kernel(
    const float* __restrict__ in_feature,
    const unsigned short* __restrict__ feat16,
    const float* __restrict__ kernel_w,
    const float* __restrict__ bias,
    const int* __restrict__ T,
    const int* __restrict__ T2, int use2,
    const int* __restrict__ ovf_cnt,
    const int* __restrict__ ovf,
    const unsigned short* __restrict__ Bf,
    float* __restrict__ out, int S2) {
  __shared__ float plane[4][16][PLPAD];       // 9216 B: per-wave partials
  __shared__ int flatE[256];                  // block's overflow entries
  __shared__ int scnt[16];

  const int tid = threadIdx.x;
  const int w = tid >> 6;
  const int lane = tid & 63;
  const int r16 = lane & 15;
  const int quad = lane >> 4;
  const int vb = blockIdx.x << 4;

  // ---- overflow staging: counts, per-thread scalar prefix, entries ----
  if (tid < 16) {
    int c = ovf_cnt[vb + tid];
    scnt[tid] = c < S2 ? c : S2;
  }
  __syncthreads();
  const int er = tid & 15;                    // (er, ej): voxel, list pos
  const int ej = tid >> 4;
  int myb = 0, tot = 0;
#pragma unroll
  for (int q = 0; q < 16; ++q) {              // scalar prefix: no priv arrays
    int cq = scnt[q];
    if (q < er) myb += cq;
    tot += cq;
  }
  if (ej < scnt[er])
    flatE[myb + ej] = (er << 24) | ovf[(ej << LOG2_NV) + vb + er];
  __syncthreads();

  // ---- dense part: both rounds' probes, then both rounds' rows ----
  const int kb = w * 7;
  const int kn = (w == 3) ? 6 : 7;
  const int v = vb + r16;
  int tv[7], tv2[7];
#pragma unroll
  for (int d = 0; d < 7; ++d)
    tv[d] = (d < kn) ? T[((kb + d) << LOG2_NV) + v] : -1;
#pragma unroll
  for (int d = 0; d < 7; ++d)
    tv2[d] = (use2 && d < kn) ? T2[((kb + d) << LOG2_NV) + v] : -1;

  bf16x8 R0[7], R1[7];
#pragma unroll
  for (int d = 0; d < 7; ++d) {
    int t = tv[d];
    int in = (t >= 0) ? (t & 0x3FFFF) : 0;
    bf16x8 a;
    if (F16) {
      a = *reinterpret_cast<const bf16x8*>(feat16 + (in << 5) + (quad << 3));
    } else {
      const float4* ap = (const float4*)(in_feature + (in << 5) + (quad << 3));
      float4 f0 = ap[0], f1 = ap[1];
      a[0] = (short)f2bf(f0.x); a[1] = (short)f2bf(f0.y);
      a[2] = (short)f2bf(f0.z); a[3] = (short)f2bf(f0.w);
      a[4] = (short)f2bf(f1.x); a[5] = (short)f2bf(f1.y);
      a[6] = (short)f2bf(f1.z); a[7] = (short)f2bf(f1.w);
    }
    if (t < 0) a = (bf16x8)0;
    R0[d] = a;
  }
#pragma unroll
  for (int d = 0; d < 7; ++d) {
    int t = tv2[d];
    int in = (t >= 0) ? (t & 0x3FFFF) : 0;
    bf16x8 a;
    if (F16) {
      a = *reinterpret_cast<const bf16x8*>(feat16 + (in << 5) + (quad << 3));
    } else {
      const float4* ap = (const float4*)(in_feature + (in << 5) + (quad << 3));
      float4 f0 = ap[0], f1 = ap[1];
      a[0] = (short)f2bf(f0.x); a[1] = (short)f2bf(f0.y);
      a[2] = (short)f2bf(f0.z); a[3] = (short)f2bf(f0.w);
      a[4] = (short)f2bf(f1.x); a[5] = (short)f2bf(f1.y);
      a[6] = (short)f2bf(f1.z); a[7] = (short)f2bf(f1.w);
    }
    if (t < 0) a = (bf16x8)0;
    R1[d] = a;
  }

  // ---- MFMA sweeps (hi-precision W only; Bf loads stay per-d) ----
  f32x4 acc0 = {0.f, 0.f, 0.f, 0.f};
  f32x4 acc1 = {0.f, 0.f, 0.f, 0.f};
  const uint4* bfp = (const uint4*)Bf;
#pragma unroll
  for (int d = 0; d < 7; ++d) {
    if (d < kn) {
      int k = kb + d;
      uint4 h0 = bfp[(k * 2 + 0) * 64 + lane];
      uint4 h1 = bfp[(k * 2 + 1) * 64 + lane];
      acc0 = __builtin_amdgcn_mfma_f32_16x16x32_bf16(
          R0[d], *reinterpret_cast<const bf16x8*>(&h0), acc0, 0, 0, 0);
      acc1 = __builtin_amdgcn_mfma_f32_16x16x32_bf16(
          R0[d], *reinterpret_cast<const bf16x8*>(&h1), acc1, 0, 0, 0);
    }
  }
  if (use2) {
#pragma unroll
    for (int d = 0; d < 7; ++d) {
      if (d < kn) {
        int k = kb + d;
        uint4 h0 = bfp[(k * 2 + 0) * 64 + lane];
        uint4 h1 = bfp[(k * 2 + 1) * 64 + lane];
        acc0 = __builtin_amdgcn_mfma_f32_16x16x32_bf16(
            R1[d], *reinterpret_cast<const bf16x8*>(&h0), acc0, 0, 0, 0);
        acc1 = __builtin_amdgcn_mfma_f32_16x16x32_bf16(
            R1[d], *reinterpret_cast<const bf16x8*>(&h1), acc1, 0, 0, 0);
      }
    }
  }

  // ---- dump partials (C/D: col=lane&15, row=quad*4+reg — m89/m91) ----
#pragma unroll
  for (int reg = 0; reg < 4; ++reg) {
    int row = quad * 4 + reg;
    plane[w][row][r16] = acc0[reg];
    plane[w][row][16 + r16] = acc1[reg];
  }

  // ---- residual overflow: entries i = w, w+4, ... ; dist-1 prefetch ----
  const int c32 = lane & 31, h = lane >> 5;
  int i = w;
  int e_cur = 0;
  float4 p0, p1, p2, p3;
  if (i < tot) {
    e_cur = flatE[i];
    const float4* ar =
        (const float4*)(in_feature + ((e_cur & 0x3FFFF) << 5) + (h << 4));
    p0 = ar[0]; p1 = ar[1]; p2 = ar[2]; p3 = ar[3];
  }
  while (i < tot) {
    const int e = e_cur;
    float4 q0 = p0, q1 = p1, q2 = p2, q3 = p3;
    const int inext = i + 4;
    if (inext < tot) {
      e_cur = flatE[inext];
      const float4* ar =
          (const float4*)(in_feature + ((e_cur & 0x3FFFF) << 5) + (h << 4));
      p0 = ar[0]; p1 = ar[1]; p2 = ar[2]; p3 = ar[3];
    }
    const int k2 = (e >> LOG2_NV) & 31;
    const int rr = (e >> 24) & 15;
    const float* wcol = kernel_w + (k2 << 10) + (h << 4) * C_CH + c32;
    float psum = 0.f;
    psum = fmaf(q0.x, wcol[0 * C_CH], psum);
    psum = fmaf(q0.y, wcol[1 * C_CH], psum);
    psum = fmaf(q0.z, wcol[2 * C_CH], psum);
    psum = fmaf(q0.w, wcol[3 * C_CH], psum);
    psum = fmaf(q1.x, wcol[4 * C_CH], psum);
    psum = fmaf(q1.y, wcol[5 * C_CH], psum);
    psum = fmaf(q1.z, wcol[6 * C_CH], psum);
    psum = fmaf(q1.w, wcol[7 * C_CH], psum);
    psum = fmaf(q2.x, wcol[8 * C_CH], psum);
    psum = fmaf(q2.y, wcol[9 * C_CH], psum);
    psum = fmaf(q2.z, wcol[10 * C_CH], psum);
    psum = fmaf(q2.w, wcol[11 * C_CH], psum);
    psum = fmaf(q3.x, wcol[12 * C_CH], psum);
    psum = fmaf(q3.y, wcol[13 * C_CH], psum);
    psum = fmaf(q3.z, wcol[14 * C_CH], psum);
    psum = fmaf(q3.w, wcol[15 * C_CH], psum);
    psum += __shfl_xor(psum, 32);
    if (h == 0) plane[w][rr][c32] += psum;    // own plane: no cross-wave race
    i = inext;
  }

  // ---- merge 4 planes + bias, one float2 store per thread ----
  __syncthreads();
  const int mr = tid >> 4;
  const int mc = (tid & 15) << 1;
  float s0 = plane[0][mr][mc] + plane[1][mr][mc] + plane[2][mr][mc] +
             plane[3][mr][mc] + bias[mc];
  float s1 = plane[0][mr][mc + 1] + plane[1][mr][mc + 1] +
             plane[2][mr][mc + 1] + plane[3][mr][mc + 1] + bias[mc + 1];
  float2 o; o.x = s0; o.y = s1;
  *(float2*)(out + ((vb + mr) << 5) + mc) = o;
}

// ---------------------------------------------------------------------------
// Emergency finisher: the ~tens of entries that overflowed S2.
__global__ __launch_bounds__(BLOCK) void emergency_kernel(
    const float* __restrict__ in_feature, const float* __restrict__ kernel_w,
    const int* __restrict__ ecnt, const int2* __restrict__ elist,
    float* __restrict__ out) {
  int e = blockIdx.x * BLOCK + threadIdx.x;
  int n = *ecnt;
  if (n > ECAP) n = ECAP;
  if (e >= n) return;
  int2 ent = elist[e];
  int v = ent.x, k = ent.y >> LOG2_NV, in = ent.y & 0x3FFFF;
  float a[C_CH];
  const float4* ar = (const float4*)(in_feature + (in << 5));
#pragma unroll
  for (int q = 0; q < 8; ++q) ((float4*)a)[q] = ar[q];
  for (int c = 0; c < C_CH; ++c) {
    float s = 0.f;
#pragma unroll
    for (int i = 0; i < C_CH; ++i)
      s = fmaf(a[i], kernel_w[(k << 10) + i * C_CH + c], s);
    atomicAdd(&out[v * C_CH + c], s);
  }
}

// ---------------------------------------------------------------------------
// Fallback (tiny ws): round-1 direct-atomic version. Correct, slow.
__global__ __launch_bounds__(BLOCK) void init_bias_kernel(
    float* __restrict__ out, const float* __restrict__ bias, int n4) {
  int idx = blockIdx.x * blockDim.x + threadIdx.x;
  if (idx >= n4) return;
  ((float4*)out)[idx] = ((const float4*)bias)[idx & 7];
}

__global__ __launch_bounds__(BLOCK) void scatter_conv_kernel(
    const float* __restrict__ in_feature, const float* __restrict__ kernel_w,
    const int* __restrict__ nbmap, float* __restrict__ out) {
  const int k = blockIdx.x >> 9;
  const int pair = blockIdx.x * BLOCK + threadIdx.x;
  const float* __restrict__ Wk = kernel_w + k * (C_CH * C_CH);
  const int2 nb = ((const int2*)nbmap)[pair];
  const float4* __restrict__ inrow =
      (const float4*)(in_feature + (long)nb.x * C_CH);
  float a[C_CH];
#pragma unroll
  for (int j = 0; j < 8; ++j) ((float4*)a)[j] = inrow[j];
  float acc[C_CH];
#pragma unroll
  for (int c = 0; c < C_CH; ++c) acc[c] = 0.0f;
#pragma unroll
  for (int i = 0; i < C_CH; ++i) {
    const float av = a[i];
#pragma unroll
    for (int c = 0; c < C_CH; ++c)
      acc[c] = fmaf(av, Wk[i * C_CH + c], acc[c]);
  }
  float* __restrict__ orow = out + (long)nb.y * C_CH;
#pragma unroll
  for (int c = 0; c < C_CH; ++c) atomicAdd(orow + c, acc[c]);
}

// ===========================================================================
extern "C" void kernel_launch(void* const* d_in, const int* in_sizes, int n_in,
                              void* d_out, int out_size, void* d_ws,
                              size_t ws_size, hipStream_t stream) {
  const float* in_feature = (const float*)d_in[0];
  const float* kernel_w   = (const float*)d_in[1];
  const float* bias       = (const float*)d_in[2];
  const int*   nbmap      = (const int*)d_in[3];
  float* out = (float*)d_out;
  const int M = in_sizes[3] / 2;                 // 3,538,944
  const int Mh = M / 2;                          // pairs of pairs

  // ws (ints): T[27N] | T2[27N if use2] | ovf_cnt[N] | ecnt[64]
  //            | elist[2*ECAP] | Bf[13824] | ovf[S2*N] | feat16[16N if use16]
  const long FIXED = 64 + 2 * ECAP + 13824;
  long ws_ints = (long)(ws_size / 4);
  long planes = (ws_ints - FIXED) / N_VOX;       // 1 MB planes
  int use2 = 0, use16 = 0;
  long s2c;
  if (planes >= 75) {                            // tier 0: T+T2+feat16+S2>=4
    use2 = 1; use16 = 1;
    s2c = planes - 71;
    if (s2c > 7) s2c = 7;
  } else if (planes >= 59) {                     // tier 1: T+T2+S2>=4
    use2 = 1;
    s2c = planes - 55;
    if (s2c > 7) s2c = 7;
  } else {                                       // tier 2: single T
    s2c = planes - 28;
    if (s2c > 15) s2c = 15;
  }
  int S2 = (int)s2c;

  if (!use2 && S2 < 4) {                         // tier 3: direct atomics
    const int n4 = out_size / 4;
    init_bias_kernel<<<(n4 + BLOCK - 1) / BLOCK, BLOCK, 0, stream>>>(out, bias,
                                                                     n4);
    scatter_conv_kernel<<<M / BLOCK, BLOCK, 0, stream>>>(in_feature, kernel_w,
                                                         nbmap, out);
    return;
  }

  const long TPLANES = (long)K3 * N_VOX;
  int* T        = (int*)d_ws;                       // [27][N_VOX]
  int* T2       = use2 ? (T + TPLANES) : T;         // [27][N_VOX]
  int* ovf_cnt  = T + TPLANES * (1 + use2);         // [N_VOX]
  int* ecnt     = ovf_cnt + N_VOX;                  // [64] (use [0])
  int2* elist   = (int2*)(ecnt + 64);               // [ECAP]
  unsigned short* Bf = (unsigned short*)(ecnt + 64 + 2 * ECAP);  // [27648]
  int* ovf      = ((int*)Bf) + 13824;               // [S2][N_VOX]
  unsigned short* feat16 = (unsigned short*)(ovf + (long)S2 * N_VOX);

  hipMemsetAsync(T, 0xFF, (size_t)TPLANES * 4 * (1 + use2), stream);
  hipMemsetAsync(ovf_cnt, 0, (size_t)(N_VOX + 64) * 4, stream);

  bf_prep_kernel<<<(FRAGN + BLOCK - 1) / BLOCK, BLOCK, 0, stream>>>(kernel_w,
                                                                    Bf);
  if (use16)
    feat16_prep_kernel<<<(N_VOX * 4) / BLOCK, BLOCK, 0, stream>>>(in_feature,
                                                                  feat16);
  passA_kernel<<<(Mh + BLOCK - 1) / BLOCK, BLOCK, 0, stream>>>(
      (const int4*)nbmap, T, Mh);
  passB_kernel<<<(Mh + BLOCK - 1) / BLOCK, BLOCK, 0, stream>>>(
      (const int4*)nbmap, T, T2, use2, ovf_cnt, ovf, S2, ecnt, elist, Mh);
  if (use16)
    gather_splitk_kernel<1><<<N_VOX / 16, BLOCK, 0, stream>>>(
        in_feature, feat16, kernel_w, bias, T, T2, use2, ovf_cnt, ovf, Bf,
        out, S2);
  else
    gather_splitk_kernel<0><<<N_VOX / 16, BLOCK, 0, stream>>>(
        in_feature, feat16, kernel_w, bias, T, T2, use2, ovf_cnt, ovf, Bf,
        out, S2);
  emergency_kernel<<<ECAP / BLOCK, BLOCK, 0, stream>>>(in_feature, kernel_w,
                                                       ecnt, elist, out);
}